// Round 8
// baseline (406.990 us; speedup 1.0000x reference)
//
#include <hip/hip_runtime.h>
#include <hip/hip_bf16.h>
#include <math.h>

#define N_TOTAL 32768
#define E_TOTAL 524288
#define NUM_GRAPHS 64
#define NPG 512
#define MAXD 64
#define KTOP 64
#define LATENT 513
#define PPAD 524

typedef __attribute__((ext_vector_type(8))) short bf16x8;
typedef __attribute__((ext_vector_type(4))) float f32x4;

__device__ __forceinline__ unsigned short f2bf(float f) {
    unsigned u = __float_as_uint(f);
    return (unsigned short)((u + 0x7FFFu + ((u >> 16) & 1u)) >> 16);   // RNE
}
__device__ __forceinline__ float bf2f(unsigned short h) {
    return __uint_as_float(((unsigned)h) << 16);
}
// XOR-swizzle within 128B granule keyed by row (G4 / rule #21: applied at ds_write AND ds_read)
__device__ __forceinline__ int swz(int bir, int row) {
    return (bir & ~127) | ((bir & 127) ^ ((row & 7) << 4));
}

// ---------------- setup ----------------

__global__ __launch_bounds__(256) void k_init(int* __restrict__ deg, int* __restrict__ cnt) {
    int i = blockIdx.x * 256 + threadIdx.x;
    if (i < N_TOTAL) { deg[i] = 1; cnt[i] = 0; }
}

__global__ __launch_bounds__(256) void k_zero(int4* __restrict__ p) {
    p[(size_t)blockIdx.x * 256 + threadIdx.x] = make_int4(0, 0, 0, 0);   // 8192 blocks = 32 MB
}

// adj/deg/cnt (for k_sort path) + packed dense counts Au[g][v][u/2] (u16 pairs)
__global__ __launch_bounds__(256) void k_build(const int* __restrict__ ei,
                                               int* __restrict__ deg, int* __restrict__ cnt,
                                               int* __restrict__ adj, unsigned* __restrict__ Au) {
    int e = blockIdx.x * 256 + threadIdx.x;
    if (e >= E_TOTAL) return;
    int s = ei[e];
    int d = ei[E_TOTAL + e];
    atomicAdd(&deg[s], 1);
    int slot = atomicAdd(&cnt[d], 1);
    if (slot < MAXD) adj[(size_t)d * MAXD + slot] = s;
    int g = d >> 9, v = d & 511, u = s & 511;
    atomicAdd(&Au[((size_t)g << 17) + (v << 8) + (u >> 1)], 1u << ((u & 1) << 4));
}

// Au counts (+I) -> dense bf16 A' [g][v][u]  (ints exact in bf16)
__global__ __launch_bounds__(256) void k_convA(const unsigned* __restrict__ Au,
                                               unsigned short* __restrict__ Asw) {
    size_t idx = (size_t)blockIdx.x * 256 + threadIdx.x;   // 2,097,152 threads
    size_t b4 = idx * 4;                                   // u32 index
    int g = (int)(b4 >> 17);
    int rem = (int)(b4 & 131071);
    int v = rem >> 8;
    int u0 = (rem & 255) * 2;
    uint4 cw = *(const uint4*)(Au + b4);
    unsigned r[4];
#pragma unroll
    for (int i = 0; i < 4; ++i) {
        unsigned wv = (&cw.x)[i];
        int ua = u0 + 2 * i, ub = ua + 1;
        float ca = (float)(wv & 0xFFFFu) + ((ua == v) ? 1.f : 0.f);
        float cb = (float)(wv >> 16)     + ((ub == v) ? 1.f : 0.f);
        r[i] = (unsigned)f2bf(ca) | ((unsigned)f2bf(cb) << 16);
    }
    *(int4*)(Asw + ((size_t)g * 512 + v) * 512 + u0) = make_int4(r[0], r[1], r[2], r[3]);
}

// W prep: transpose + bf16 hi/lo split (unchanged, proven)
__global__ __launch_bounds__(256) void k_prep(const float* __restrict__ Wc,
                                              unsigned short* __restrict__ Wth,
                                              unsigned short* __restrict__ Wtl) {
    __shared__ float tile[64][65];
    int b = blockIdx.x;
    int l = b >> 2, t = b & 3;
    int k0 = (t >> 1) * 64, o0 = (t & 1) * 64;
    int lane = threadIdx.x & 63, q = threadIdx.x >> 6;
    const float* Wsrc = Wc + (size_t)l * 16384;
#pragma unroll
    for (int it = 0; it < 16; ++it) {
        int r = it * 4 + q;
        tile[r][lane] = Wsrc[(size_t)(k0 + r) * 128 + o0 + lane];
    }
    __syncthreads();
#pragma unroll
    for (int it = 0; it < 16; ++it) {
        int o = it * 4 + q;
        float v = tile[lane][o];
        unsigned short h = f2bf(v);
        unsigned short lo = f2bf(v - bf2f(h));
        size_t dst = (size_t)l * 16384 + (size_t)(o0 + o) * 128 + k0 + lane;
        Wth[dst] = h; Wtl[dst] = lo;
    }
}

// layer-0 panels: emb[x[.]] -> transposed hi/lo panels [g][128ch][512u]
__global__ __launch_bounds__(256) void k_embT(const int* __restrict__ x,
                                              const float* __restrict__ emb,
                                              unsigned short* __restrict__ Ph,
                                              unsigned short* __restrict__ Pl) {
    __shared__ float P[64][132];
    __shared__ int nodes[64];
    int b = blockIdx.x;               // 512 blocks: graph x 8 chunks of 64 nodes
    int g = b >> 3, ck = b & 7;
    int tid = threadIdx.x;
    if (tid < 64) nodes[tid] = x[g * NPG + ck * 64 + tid];
    __syncthreads();
#pragma unroll
    for (int c = 0; c < 8; ++c) {
        int idx = tid + c * 256;      // 2048 float4 units
        int row = idx >> 5, c4 = idx & 31;
        float4 vv = *(const float4*)(emb + (size_t)nodes[row] * 128 + c4 * 4);
        *(float4*)&P[row][c4 * 4] = vv;
    }
    __syncthreads();
#pragma unroll
    for (int c = 0; c < 4; ++c) {
        int idx = tid + c * 256;      // 1024: ch x 8-node group
        int ch = idx >> 3, grp = idx & 7;
        unsigned hw[4], lw[4];
#pragma unroll
        for (int j = 0; j < 4; ++j) {
            float a  = P[grp * 8 + 2 * j][ch];
            float bq = P[grp * 8 + 2 * j + 1][ch];
            unsigned short ha = f2bf(a),  hb = f2bf(bq);
            unsigned short la = f2bf(a - bf2f(ha)), lb = f2bf(bq - bf2f(hb));
            hw[j] = (unsigned)ha | ((unsigned)hb << 16);
            lw[j] = (unsigned)la | ((unsigned)lb << 16);
        }
        size_t base = ((size_t)g * 128 + ch) * 512 + ck * 64 + grp * 8;
        *(int4*)(Ph + base) = make_int4(hw[0], hw[1], hw[2], hw[3]);
        *(int4*)(Pl + base) = make_int4(lw[0], lw[1], lw[2], lw[3]);
    }
}

// ---------------- fused layer, fully dense MFMA ----------------
// 512 blocks (graph x 8 v-blocks of 64). Phase1: S[64v][128ch] = A'[64][512] @ (Hh+Hl)
// Phase2: Hout = tanh((S@W + (cnt+1)b)/deg); writes Hout f32, next-layer panels, tmp (l3).

__global__ __launch_bounds__(256) void k_layer(const unsigned short* __restrict__ Ph,
                                               const unsigned short* __restrict__ Pl,
                                               const unsigned short* __restrict__ Asw,
                                               const unsigned short* __restrict__ Wth,
                                               const unsigned short* __restrict__ Wtl,
                                               const float* __restrict__ bvec,
                                               const float* __restrict__ Wl,
                                               const float* __restrict__ bl,
                                               float* __restrict__ tmp,
                                               float* __restrict__ Hout,
                                               unsigned short* __restrict__ Poh,
                                               unsigned short* __restrict__ Pol,
                                               const int* __restrict__ cnt,
                                               const int* __restrict__ deg) {
    __shared__ char lds[40960];   // [0,8K)=A-tile 64x128B; [8K,24K)=Hh/Sb-hi; [24K,40K)=Hl/Sb-lo
    int tid = threadIdx.x;
    int w = tid >> 6, lane = tid & 63;
    int bid = blockIdx.x;
    int g = (bid & 7) * 8 + ((bid >> 3) & 7);   // 8 graphs per XCD
    int vblk = bid >> 6;                        // 0..7
    int nodebase = g * NPG + vblk * 64;
    int r = lane & 15, kb = lane >> 4;

    // ---- phase 1: K-loop over 512 u in 8 tiles of 64 ----
    f32x4 acc[8];
#pragma unroll
    for (int n = 0; n < 8; ++n) acc[n] = (f32x4){0.f, 0.f, 0.f, 0.f};
    size_t Abase = ((size_t)(g * NPG + vblk * 64)) * 512;
    int vrow = w * 16 + r;

    for (int kt = 0; kt < 8; ++kt) {
        // stage 40KB: reg-staged with swizzled ds_write (globals stay plain)
#pragma unroll
        for (int c = 0; c < 10; ++c) {
            int idx = tid + c * 256;      // [0,2560) 16B units; 256-aligned regions
            const unsigned short* src;
            int row, off16, ldsbase;
            if (idx < 512)       { row = idx >> 3;          off16 = idx & 7;
                src = Asw + Abase + (size_t)row * 512 + kt * 64 + off16 * 8;
                ldsbase = 0; }
            else if (idx < 1536) { int j = idx - 512;  row = j >> 3; off16 = j & 7;
                src = Ph + ((size_t)g * 128 + row) * 512 + kt * 64 + off16 * 8;
                ldsbase = 8192; }
            else                 { int j = idx - 1536; row = j >> 3; off16 = j & 7;
                src = Pl + ((size_t)g * 128 + row) * 512 + kt * 64 + off16 * 8;
                ldsbase = 24576; }
            int4 v = *(const int4*)src;
            *(int4*)(lds + ldsbase + row * 128 + swz(off16 * 16, row)) = v;
        }
        __syncthreads();
#pragma unroll
        for (int s2 = 0; s2 < 2; ++s2) {
            int bir = s2 * 64 + kb * 16;
            bf16x8 aA = *(const bf16x8*)(lds + vrow * 128 + swz(bir, vrow));
#pragma unroll
            for (int n = 0; n < 8; ++n) {
                int ch = n * 16 + r;
                bf16x8 bh = *(const bf16x8*)(lds + 8192  + ch * 128 + swz(bir, ch));
                bf16x8 bl2 = *(const bf16x8*)(lds + 24576 + ch * 128 + swz(bir, ch));
                acc[n] = __builtin_amdgcn_mfma_f32_16x16x32_bf16(aA, bh,  acc[n], 0, 0, 0);
                acc[n] = __builtin_amdgcn_mfma_f32_16x16x32_bf16(aA, bl2, acc[n], 0, 0, 0);
            }
        }
        __syncthreads();
    }

    // ---- S -> Sb hi/lo in LDS (own-wave rows; region reuses Hh/Hl tiles) ----
#pragma unroll
    for (int n = 0; n < 8; ++n) {
#pragma unroll
        for (int q = 0; q < 4; ++q) {
            int v64 = w * 16 + kb * 4 + q;
            int ch = n * 16 + r;
            float s = acc[n][q];
            unsigned short h = f2bf(s), lo = f2bf(s - bf2f(h));
            int addr = v64 * 256 + swz(ch * 2, v64);
            *(unsigned short*)(lds + 8192 + addr)  = h;
            *(unsigned short*)(lds + 24576 + addr) = lo;
        }
    }
    __syncthreads();

    // ---- phase 2: Hout = tanh((S@W + (cnt+1)b)/deg) ----
    int rowbase = nodebase + w * 16;
    bf16x8 ah[4], al[4];
#pragma unroll
    for (int ks = 0; ks < 4; ++ks) {
        int v64 = w * 16 + r;
        int addr = v64 * 256 + swz(ks * 64 + kb * 16, v64);
        ah[ks] = *(const bf16x8*)(lds + 8192 + addr);
        al[ks] = *(const bf16x8*)(lds + 24576 + addr);
    }
    float invd[4], cp1[4];
#pragma unroll
    for (int q = 0; q < 4; ++q) {
        int nd = rowbase + kb * 4 + q;
        invd[q] = 1.0f / (float)deg[nd];
        cp1[q]  = (float)(cnt[nd] + 1);
    }
    float z[4] = {0.f, 0.f, 0.f, 0.f};
    unsigned hiW[8][2], loW[8][2];
#pragma unroll
    for (int ct = 0; ct < 8; ++ct) {
        const unsigned short* Wh = Wth + (size_t)(ct * 16 + r) * 128;
        const unsigned short* Wo = Wtl + (size_t)(ct * 16 + r) * 128;
        f32x4 a = {0.f, 0.f, 0.f, 0.f};
#pragma unroll
        for (int ks = 0; ks < 4; ++ks) {
            bf16x8 wh = *(const bf16x8*)(Wh + ks * 32 + kb * 8);
            bf16x8 wl = *(const bf16x8*)(Wo + ks * 32 + kb * 8);
            a = __builtin_amdgcn_mfma_f32_16x16x32_bf16(ah[ks], wh, a, 0, 0, 0);
            a = __builtin_amdgcn_mfma_f32_16x16x32_bf16(ah[ks], wl, a, 0, 0, 0);
            a = __builtin_amdgcn_mfma_f32_16x16x32_bf16(al[ks], wh, a, 0, 0, 0);
        }
        float bcol = bvec[ct * 16 + r];
        float wlast = Wl ? Wl[ct * 16 + r] : 0.f;
        unsigned short hq[4], lq[4];
#pragma unroll
        for (int q = 0; q < 4; ++q) {
            float val = tanhf((a[q] + bcol * cp1[q]) * invd[q]);
            Hout[(size_t)(rowbase + kb * 4 + q) * 128 + ct * 16 + r] = val;
            z[q] = fmaf(val, wlast, z[q]);
            hq[q] = f2bf(val);
            lq[q] = f2bf(val - bf2f(hq[q]));
        }
        hiW[ct][0] = (unsigned)hq[0] | ((unsigned)hq[1] << 16);
        hiW[ct][1] = (unsigned)hq[2] | ((unsigned)hq[3] << 16);
        loW[ct][0] = (unsigned)lq[0] | ((unsigned)lq[1] << 16);
        loW[ct][1] = (unsigned)lq[2] | ((unsigned)lq[3] << 16);
    }

    // ---- next-layer panels via LDS-bounce transpose (Th@0, Tl@16K) ----
    if (Poh) {
        __syncthreads();                         // all Sb reads done before overwrite
#pragma unroll
        for (int ct = 0; ct < 8; ++ct) {
            int o = ct * 16 + r;
            int v64 = w * 16 + kb * 4;
            int addr = o * 128 + swz(v64 * 2, o);          // 8B-aligned
            *(int2*)(lds + addr)         = make_int2(hiW[ct][0], hiW[ct][1]);
            *(int2*)(lds + 16384 + addr) = make_int2(loW[ct][0], loW[ct][1]);
        }
        __syncthreads();
#pragma unroll
        for (int c = 0; c < 8; ++c) {
            int idx = tid + c * 256;             // 2048 16B units
            int arr = idx >> 10;
            int j = idx & 1023;
            int o = j >> 3, off16 = j & 7;
            int4 v = *(const int4*)(lds + arr * 16384 + o * 128 + swz(off16 * 16, o));
            unsigned short* dst = (arr ? Pol : Poh) + ((size_t)g * 128 + o) * 512 + vblk * 64 + off16 * 8;
            *(int4*)dst = v;
        }
    }

    // ---- fused last_lin (layer 3) ----
    if (Wl) {
#pragma unroll
        for (int m = 1; m < 16; m <<= 1) {
            z[0] += __shfl_xor(z[0], m); z[1] += __shfl_xor(z[1], m);
            z[2] += __shfl_xor(z[2], m); z[3] += __shfl_xor(z[3], m);
        }
        if (r == 0) {
            float b0 = bl[0];
#pragma unroll
            for (int q = 0; q < 4; ++q) tmp[rowbase + kb * 4 + q] = z[q] + b0;
        }
    }
}

// ---------------- sort pool (fused last-channel agg + exact bitonic) ----------------

__global__ __launch_bounds__(256) void k_sort(const float* __restrict__ tmp,
                                              const int* __restrict__ adj,
                                              const int* __restrict__ cnt,
                                              const int* __restrict__ deg,
                                              float* __restrict__ lastc,
                                              int* __restrict__ topk) {
    __shared__ float v[512];
    __shared__ int ix[512];
    int g = blockIdx.x, tid = threadIdx.x;
    for (int i = tid; i < 512; i += 256) {
        int node = g * NPG + i;
        float s = tmp[node];
        int c = cnt[node]; if (c > MAXD) c = MAXD;
        const int* av = adj + (size_t)node * MAXD;
#pragma unroll 4
        for (int q = 0; q < c; ++q) s += tmp[av[q]];
        float val = tanhf(s / (float)deg[node]);
        lastc[node] = val;
        v[i] = val; ix[i] = i;
    }
    __syncthreads();
    for (int ksz = 2; ksz <= 512; ksz <<= 1) {
        for (int jj = ksz >> 1; jj > 0; jj >>= 1) {
            for (int i = tid; i < 512; i += 256) {
                int p = i ^ jj;
                if (p > i) {
                    float va = v[i], vb = v[p];
                    int ia = ix[i], ib = ix[p];
                    bool b_before_a = (vb > va) || (vb == va && ib < ia);
                    bool up = (i & ksz) == 0;
                    bool sw = up ? b_before_a : !b_before_a;
                    if (sw) { v[i] = vb; v[p] = va; ix[i] = ib; ix[p] = ia; }
                }
            }
            __syncthreads();
        }
    }
    for (int k = tid; k < KTOP; k += 256) topk[g * KTOP + k] = g * NPG + ix[k];
}

// ---------------- conv1 + relu + maxpool ----------------

__global__ __launch_bounds__(256) void k_conv1(const int* __restrict__ topk,
                                               const float* __restrict__ h0,
                                               const float* __restrict__ h1,
                                               const float* __restrict__ h2,
                                               const float* __restrict__ h3,
                                               const float* __restrict__ lastc,
                                               const float* __restrict__ c1w,
                                               const float* __restrict__ c1b,
                                               float* __restrict__ y1p) {
    __shared__ float P[16][PPAD];
    __shared__ float Y1c[16][16];
    __shared__ int nodes[16];
    int bid = blockIdx.x;
    int g = bid >> 2, cc = bid & 3;
    int tid = threadIdx.x;
    if (tid < 16) nodes[tid] = topk[g * KTOP + cc * 16 + tid];
    __syncthreads();
    {
        int r = tid >> 4, t4 = tid & 15;
        int node = nodes[r];
#pragma unroll
        for (int jj = 0; jj < 8; ++jj) {
            int d = (t4 + 16 * jj) * 4;
            const float* src = (d < 128) ? h0 : (d < 256) ? h1 : (d < 384) ? h2 : h3;
            float4 val = *(const float4*)(src + (size_t)node * 128 + (d & 127));
            *(float4*)&P[r][d] = val;
        }
        if (t4 == 0) P[r][512] = lastc[node];
    }
    __syncthreads();
    int o = tid >> 4, kk = tid & 15;
    const float* w = c1w + (size_t)o * LATENT;
    float a0 = 0.f, a1 = 0.f, a2 = 0.f, a3 = 0.f;
    for (int d = 0; d < 512; d += 4) {
        float4 p = *(const float4*)&P[kk][d];
        a0 = fmaf(p.x, w[d],     a0);
        a1 = fmaf(p.y, w[d + 1], a1);
        a2 = fmaf(p.z, w[d + 2], a2);
        a3 = fmaf(p.w, w[d + 3], a3);
    }
    float s = ((a0 + a1) + (a2 + a3)) + P[kk][512] * w[512] + c1b[o];
    Y1c[o][kk] = fmaxf(s, 0.f);
    __syncthreads();
    if (tid < 128) {
        int oo = tid >> 3, l = tid & 7;
        y1p[(size_t)g * 512 + oo * 32 + cc * 8 + l] = fmaxf(Y1c[oo][2 * l], Y1c[oo][2 * l + 1]);
    }
}

// ---------------- conv2 + dense + softmax ----------------

__global__ __launch_bounds__(256) void k_tail(const float* __restrict__ y1p,
                                              const float* __restrict__ c2w, const float* __restrict__ c2b,
                                              const float* __restrict__ d1w, const float* __restrict__ d1b,
                                              const float* __restrict__ d2w, const float* __restrict__ d2b,
                                              float* __restrict__ out) {
    __shared__ float Y1P[16][32];
    __shared__ float Y2[32][28];
    __shared__ float H1s[32];
    __shared__ float red[256];
    int g = blockIdx.x, tid = threadIdx.x;
    for (int t = tid; t < 512; t += 256) ((float*)Y1P)[t] = y1p[(size_t)g * 512 + t];
    __syncthreads();
    for (int t = tid; t < 32 * 28; t += 256) {
        int o2 = t / 28, tt = t - o2 * 28;
        float s = c2b[o2];
#pragma unroll
        for (int i = 0; i < 16; ++i)
#pragma unroll
            for (int dt = 0; dt < 5; ++dt)
                s = fmaf(Y1P[i][tt + dt], c2w[o2 * 80 + i * 5 + dt], s);
        Y2[o2][tt] = fmaxf(s, 0.f);
    }
    __syncthreads();
    {
        int jcol = tid >> 3, part = tid & 7;
        float s = 0.f;
        for (int rr = 0; rr < 4; ++rr) {
            int o2 = part * 4 + rr;
            int base = o2 * 28;
            for (int tt = 0; tt < 28; ++tt)
                s = fmaf(Y2[o2][tt], d1w[(size_t)(base + tt) * 32 + jcol], s);
        }
        red[tid] = s;
        __syncthreads();
        if (part == 0) {
            float t = 0.f;
#pragma unroll
            for (int p = 0; p < 8; ++p) t += red[tid + p];
            H1s[jcol] = fmaxf(t + d1b[jcol], 0.f);
        }
        __syncthreads();
    }
    if (tid == 0) {
        float l0 = d2b[0], l1 = d2b[1];
        for (int jc = 0; jc < 32; ++jc) {
            l0 = fmaf(H1s[jc], d2w[jc * 2 + 0], l0);
            l1 = fmaf(H1s[jc], d2w[jc * 2 + 1], l1);
        }
        float m = fmaxf(l0, l1);
        float e0 = expf(l0 - m), e1 = expf(l1 - m);
        float inv = 1.f / (e0 + e1);
        out[g * 2 + 0] = e0 * inv;
        out[g * 2 + 1] = e1 * inv;
    }
}

// ---------------- launch ----------------

extern "C" void kernel_launch(void* const* d_in, const int* in_sizes, int n_in,
                              void* d_out, int out_size, void* d_ws, size_t ws_size,
                              hipStream_t stream) {
    const int*   x    = (const int*)d_in[0];
    const int*   ei   = (const int*)d_in[1];
    const float* emb  = (const float*)d_in[3];
    const float* Wc   = (const float*)d_in[4];
    const float* bc   = (const float*)d_in[5];
    const float* Wl   = (const float*)d_in[6];
    const float* bl   = (const float*)d_in[7];
    const float* c1w  = (const float*)d_in[8];
    const float* c1b  = (const float*)d_in[9];
    const float* c2w  = (const float*)d_in[10];
    const float* c2b  = (const float*)d_in[11];
    const float* d1w  = (const float*)d_in[12];
    const float* d1b  = (const float*)d_in[13];
    const float* d2w  = (const float*)d_in[14];
    const float* d2b  = (const float*)d_in[15];
    float* out = (float*)d_out;

    char* ws = (char*)d_ws;
    int*   deg  = (int*)ws;            ws += (size_t)N_TOTAL * 4;
    int*   cnt  = (int*)ws;            ws += (size_t)N_TOTAL * 4;
    int*   adj  = (int*)ws;            ws += (size_t)N_TOTAL * MAXD * 4;
    float* Hid0 = (float*)ws;          ws += (size_t)N_TOTAL * 128 * 4;
    float* Hid1 = (float*)ws;          ws += (size_t)N_TOTAL * 128 * 4;
    float* Hid2 = (float*)ws;          ws += (size_t)N_TOTAL * 128 * 4;
    float* Hid3 = (float*)ws;          ws += (size_t)N_TOTAL * 128 * 4;
    unsigned short* Wth = (unsigned short*)ws;  ws += (size_t)4 * 128 * 128 * 2;
    unsigned short* Wtl = (unsigned short*)ws;  ws += (size_t)4 * 128 * 128 * 2;
    float* tmp  = (float*)ws;          ws += (size_t)N_TOTAL * 4;
    float* lastc= (float*)ws;          ws += (size_t)N_TOTAL * 4;
    int*   topk = (int*)ws;            ws += (size_t)NUM_GRAPHS * KTOP * 4;
    float* y1p  = (float*)ws;          ws += (size_t)NUM_GRAPHS * 16 * 32 * 4;
    unsigned* Au = (unsigned*)ws;      ws += (size_t)NUM_GRAPHS * 512 * 256 * 4;   // 32 MB
    unsigned short* Asw = (unsigned short*)ws;  ws += (size_t)NUM_GRAPHS * 512 * 512 * 2; // 32 MB
    unsigned short* PAh = (unsigned short*)ws;  ws += (size_t)NUM_GRAPHS * 128 * 512 * 2;
    unsigned short* PAl = (unsigned short*)ws;  ws += (size_t)NUM_GRAPHS * 128 * 512 * 2;
    unsigned short* PBh = (unsigned short*)ws;  ws += (size_t)NUM_GRAPHS * 128 * 512 * 2;
    unsigned short* PBl = (unsigned short*)ws;  ws += (size_t)NUM_GRAPHS * 128 * 512 * 2;

    k_init <<<N_TOTAL / 256, 256, 0, stream>>>(deg, cnt);
    k_zero <<<8192, 256, 0, stream>>>((int4*)Au);
    k_build<<<E_TOTAL / 256, 256, 0, stream>>>(ei, deg, cnt, adj, Au);
    k_prep <<<16, 256, 0, stream>>>(Wc, Wth, Wtl);
    k_convA<<<8192, 256, 0, stream>>>(Au, Asw);
    k_embT <<<NUM_GRAPHS * 8, 256, 0, stream>>>(x, emb, PAh, PAl);

    float* Hids[4] = {Hid0, Hid1, Hid2, Hid3};
    unsigned short* Pin_h[4] = {PAh, PBh, PAh, PBh};
    unsigned short* Pin_l[4] = {PAl, PBl, PAl, PBl};
    unsigned short* Pout_h[4] = {PBh, PAh, PBh, nullptr};
    unsigned short* Pout_l[4] = {PBl, PAl, PBl, nullptr};
    for (int l = 0; l < 4; ++l) {
        const float* wl  = (l == 3) ? Wl : nullptr;
        const float* blp = (l == 3) ? bl : nullptr;
        float*       tp  = (l == 3) ? tmp : nullptr;
        k_layer<<<512, 256, 0, stream>>>(Pin_h[l], Pin_l[l], Asw,
                                         Wth + (size_t)l * 16384, Wtl + (size_t)l * 16384,
                                         bc + (size_t)l * 128, wl, blp, tp,
                                         Hids[l], Pout_h[l], Pout_l[l], cnt, deg);
    }
    k_sort <<<NUM_GRAPHS, 256, 0, stream>>>(tmp, adj, cnt, deg, lastc, topk);
    k_conv1<<<NUM_GRAPHS * 4, 256, 0, stream>>>(topk, Hid0, Hid1, Hid2, Hid3, lastc, c1w, c1b, y1p);
    k_tail <<<NUM_GRAPHS, 256, 0, stream>>>(y1p, c2w, c2b, d1w, d1b, d2w, d2b, out);
}